// Round 7
// baseline (1019.771 us; speedup 1.0000x reference)
//
#include <hip/hip_runtime.h>
#include <hip/hip_bf16.h>

// GCN-VAE encoder: mu = S(xW_mu)+b_mu, logstd = S(xW_ls)+b_ls
// S = D^-1/2 (A+I) D^-1/2  (in-degree by dst, self-loops included)
//
// R5 measured: total 908us; k_out (CSR gather) 228us top; ~680us hidden in
// build+gemm. R6/7: k_gemm 128x128/8x8 with transposed-x LDS (4x ds_read_b128
// per 64 FMA), vectorized count/fill. k_out untouched (validated).
//
// Pipeline:
//  1. k_detect : int64 vs int32 edge_index (data-driven, graph-capture safe)
//  2. k_zero   : cnt = cursor = 0
//  3. k_count  : cnt[dst]++ (4 edges/thread, vector loads)
//  4. k_scan   : rowptr = exclusive_scan(cnt)  (single-WG 1024-thread scan)
//  5. k_dinv   : dinv[i] = rsqrt(cnt[i]+1)     (+1 = self-loop)
//  6. k_fill   : esrc[rowptr[d] + cursor[d]++] = s   (4 edges/thread loads)
//  7. k_gemm   : h[N][128] = x @ [W_mu | W_ls]  (fp32, 128x128 tile, 8x8/thread)
//  8. k_out    : 1 wave/node: acc = dinv[i]^2*h[i] + sum_e dinv[s]dinv[i]*h[s]

#define IN_C 256
#define HC   128   // concatenated output channels (64 mu + 64 ls)
#define OC   64

// ---------------------------------------------------------------- detect
__global__ void k_detect(const void* ei, int n_scan, long long nn, int* flag) {
    __shared__ int bad;
    if (threadIdx.x == 0) bad = 0;
    __syncthreads();
    const long long* p = (const long long*)ei;
    for (int i = threadIdx.x; i < n_scan; i += blockDim.x) {
        long long v = p[i];
        if (v < 0 || v >= nn) bad = 1;   // benign race
    }
    __syncthreads();
    if (threadIdx.x == 0) *flag = bad;   // 1 => data is int32, 0 => int64
}

// ---------------------------------------------------------------- zero
__global__ __launch_bounds__(256) void k_zero(int* cnt, int* cursor, int n) {
    int i = blockIdx.x * 256 + threadIdx.x;
    if (i < n) { cnt[i] = 0; cursor[i] = 0; }
}

// ---------------------------------------------------------------- count in-degree
// 4 edges per thread, vectorized loads of the dst half.
__global__ __launch_bounds__(256) void k_count(const void* ei, int* cnt, int E, const int* flag) {
    int e0 = (blockIdx.x * 256 + threadIdx.x) * 4;
    if (e0 >= E) return;
    if (e0 + 3 < E) {
        int d[4];
        if (*flag) {
            int4 v = *(const int4*)((const int*)ei + (size_t)E + e0);
            d[0] = v.x; d[1] = v.y; d[2] = v.z; d[3] = v.w;
        } else {
            const long long* p = (const long long*)ei + (size_t)E + e0;
            longlong2 a = *(const longlong2*)p;
            longlong2 b = *(const longlong2*)(p + 2);
            d[0] = (int)a.x; d[1] = (int)a.y; d[2] = (int)b.x; d[3] = (int)b.y;
        }
        #pragma unroll
        for (int u = 0; u < 4; ++u) atomicAdd(&cnt[d[u]], 1);
    } else {
        for (int e = e0; e < E; ++e) {
            int d = (*flag) ? ((const int*)ei)[(size_t)E + e]
                            : (int)((const long long*)ei)[(size_t)E + e];
            atomicAdd(&cnt[d], 1);
        }
    }
}

// ---------------------------------------------------------------- exclusive scan
// Single workgroup, 1024 threads, each owns a contiguous chunk of ~n/1024.
__global__ void k_scan(const int* __restrict__ cnt, int* __restrict__ rowptr, int n) {
    __shared__ int part[1024];
    const int tid = threadIdx.x;
    const int per = (n + 1023) >> 10;
    const int lo  = tid * per;
    const int hi  = min(lo + per, n);
    int s = 0;
    for (int i = lo; i < hi; ++i) s += cnt[i];
    part[tid] = s;
    __syncthreads();
    for (int off = 1; off < 1024; off <<= 1) {   // inclusive Hillis-Steele
        int v = (tid >= off) ? part[tid - off] : 0;
        __syncthreads();
        part[tid] += v;
        __syncthreads();
    }
    int run = (tid > 0) ? part[tid - 1] : 0;     // exclusive base for my chunk
    for (int i = lo; i < hi; ++i) { rowptr[i] = run; run += cnt[i]; }
    if (hi == n) rowptr[n] = run;                // total (benign multi-write)
}

// ---------------------------------------------------------------- dinv
__global__ __launch_bounds__(256) void k_dinv(const int* __restrict__ cnt, float* dinv, int n) {
    int i = blockIdx.x * 256 + threadIdx.x;
    if (i < n) dinv[i] = rsqrtf((float)(cnt[i] + 1));
}

// ---------------------------------------------------------------- CSR fill
// 4 edges per thread, vectorized loads of src and dst halves.
__global__ __launch_bounds__(256) void k_fill(const void* ei, const int* __restrict__ rowptr,
                                              int* cursor, int* __restrict__ esrc,
                                              int E, const int* flag) {
    int e0 = (blockIdx.x * 256 + threadIdx.x) * 4;
    if (e0 >= E) return;
    if (e0 + 3 < E) {
        int s[4], d[4];
        if (*flag) {
            int4 vs = *(const int4*)((const int*)ei + e0);
            int4 vd = *(const int4*)((const int*)ei + (size_t)E + e0);
            s[0] = vs.x; s[1] = vs.y; s[2] = vs.z; s[3] = vs.w;
            d[0] = vd.x; d[1] = vd.y; d[2] = vd.z; d[3] = vd.w;
        } else {
            const long long* ps = (const long long*)ei + e0;
            const long long* pd = (const long long*)ei + (size_t)E + e0;
            longlong2 a = *(const longlong2*)ps;
            longlong2 b = *(const longlong2*)(ps + 2);
            longlong2 c = *(const longlong2*)pd;
            longlong2 g = *(const longlong2*)(pd + 2);
            s[0] = (int)a.x; s[1] = (int)a.y; s[2] = (int)b.x; s[3] = (int)b.y;
            d[0] = (int)c.x; d[1] = (int)c.y; d[2] = (int)g.x; d[3] = (int)g.y;
        }
        #pragma unroll
        for (int u = 0; u < 4; ++u) {
            int pos = rowptr[d[u]] + atomicAdd(&cursor[d[u]], 1);
            esrc[pos] = s[u];
        }
    } else {
        for (int e = e0; e < E; ++e) {
            int s, d;
            if (*flag) {
                s = ((const int*)ei)[e]; d = ((const int*)ei)[(size_t)E + e];
            } else {
                s = (int)((const long long*)ei)[e]; d = (int)((const long long*)ei)[(size_t)E + e];
            }
            int pos = rowptr[d] + atomicAdd(&cursor[d], 1);
            esrc[pos] = s;
        }
    }
}

// ---------------------------------------------------------------- GEMM v2
// h[N][128] = x[N][256] @ [W_mu | W_ls][256][128]
// 128x128 block tile, 256 threads, 8x8 thread tile.
// x staged TRANSPOSED (xsT[k][row]) so the A fragment is 2x ds_read_b128;
// W staged row-major (wsm[k][col]), B fragment 2x ds_read_b128.
// Accumulation order over k is identical to v1 (ascending) -> same numerics.
#define BR2 128
#define KC2 32
#define STX 132   // padded row stride (floats); 132%4==0 keeps b128 alignment,
                  // 132%32==4 spreads staging-write banks
__global__ __launch_bounds__(256) void k_gemm(const float* __restrict__ x,
                                              const float* __restrict__ Wmu,
                                              const float* __restrict__ Wls,
                                              float* __restrict__ hout, int nrows) {
    __shared__ float xsT[KC2][STX];
    __shared__ float wsm[KC2][STX];
    const int tid  = threadIdx.x;
    const int trow = tid >> 4;            // 0..15
    const int tcol = tid & 15;            // 0..15
    const int r0   = trow * 8;
    const int c0   = tcol * 8;
    const size_t rowbase = (size_t)blockIdx.x * BR2;

    float acc[8][8];
    #pragma unroll
    for (int i = 0; i < 8; ++i)
        #pragma unroll
        for (int j = 0; j < 8; ++j) acc[i][j] = 0.0f;

    for (int kc = 0; kc < IN_C; kc += KC2) {
        __syncthreads();
        // stage x transposed: 128 rows x 32 k = 1024 float4 loads / 256 thr = 4 each
        // lane layout: kq = tid&7 (float4 index along k), row = tid>>3 (+32/iter)
        {
            int kq  = tid & 7;
            int row = tid >> 3;
            #pragma unroll
            for (int it = 0; it < 4; ++it) {
                int r = row + it * 32;
                size_t gr = rowbase + r;
                float4 v = make_float4(0.f, 0.f, 0.f, 0.f);
                if (gr < (size_t)nrows)
                    v = *(const float4*)(x + gr * IN_C + kc + kq * 4);
                xsT[kq * 4 + 0][r] = v.x;
                xsT[kq * 4 + 1][r] = v.y;
                xsT[kq * 4 + 2][r] = v.z;
                xsT[kq * 4 + 3][r] = v.w;
            }
        }
        // stage W: 32 k x 128 ch = 1024 float4 / 256 thr = 4 each
        #pragma unroll
        for (int it = 0; it < 4; ++it) {
            int q  = tid + 256 * it;
            int k  = q >> 5;
            int cq = (q & 31) * 4;
            const float* srcw = (cq < OC) ? (Wmu + (size_t)(kc + k) * OC + cq)
                                          : (Wls + (size_t)(kc + k) * OC + (cq - OC));
            *(float4*)&wsm[k][cq] = *(const float4*)srcw;
        }
        __syncthreads();

        #pragma unroll
        for (int k = 0; k < KC2; ++k) {
            float4 a0 = *(const float4*)&xsT[k][r0];
            float4 a1 = *(const float4*)&xsT[k][r0 + 4];
            float4 w0 = *(const float4*)&wsm[k][c0];
            float4 w1 = *(const float4*)&wsm[k][c0 + 4];
            float av[8] = {a0.x, a0.y, a0.z, a0.w, a1.x, a1.y, a1.z, a1.w};
            float wv[8] = {w0.x, w0.y, w0.z, w0.w, w1.x, w1.y, w1.z, w1.w};
            #pragma unroll
            for (int i = 0; i < 8; ++i)
                #pragma unroll
                for (int j = 0; j < 8; ++j)
                    acc[i][j] += av[i] * wv[j];
        }
    }
    #pragma unroll
    for (int i = 0; i < 8; ++i) {
        size_t gr = rowbase + r0 + i;
        if (gr < (size_t)nrows) {
            *(float4*)(hout + gr * HC + c0)     = make_float4(acc[i][0], acc[i][1], acc[i][2], acc[i][3]);
            *(float4*)(hout + gr * HC + c0 + 4) = make_float4(acc[i][4], acc[i][5], acc[i][6], acc[i][7]);
        }
    }
}

// ---------------------------------------------------------------- per-node gather
// One wave (64 lanes) per node; lane owns channels 2*lane, 2*lane+1 (float2).
// 8-deep gather unroll for MLP (mean degree = E/N = 32).
__global__ __launch_bounds__(256) void k_out(const float* __restrict__ h,
                                             const int* __restrict__ rowptr,
                                             const int* __restrict__ esrc,
                                             const float* __restrict__ dinv,
                                             const float* __restrict__ bmu,
                                             const float* __restrict__ bls,
                                             float* __restrict__ out_mu,
                                             float* __restrict__ out_ls, int n) {
    int node = blockIdx.x * 4 + (threadIdx.x >> 6);
    if (node >= n) return;
    int lane = threadIdx.x & 63;
    const float2* __restrict__ h2 = (const float2*)h;

    float di = dinv[node];
    float2 self = h2[(size_t)node * 64 + lane];
    float w  = di * di;
    float ax = self.x * w, ay = self.y * w;

    int k   = rowptr[node];
    int end = rowptr[node + 1];

    for (; k + 7 < end; k += 8) {
        int   s[8];
        float nm[8];
        float2 v[8];
        #pragma unroll
        for (int u = 0; u < 8; ++u) s[u] = esrc[k + u];
        #pragma unroll
        for (int u = 0; u < 8; ++u) nm[u] = dinv[s[u]] * di;
        #pragma unroll
        for (int u = 0; u < 8; ++u) v[u] = h2[(size_t)s[u] * 64 + lane];
        #pragma unroll
        for (int u = 0; u < 8; ++u) { ax += v[u].x * nm[u]; ay += v[u].y * nm[u]; }
    }
    for (; k < end; ++k) {
        int s0 = esrc[k];
        float n0 = dinv[s0] * di;
        float2 v0 = h2[(size_t)s0 * 64 + lane];
        ax += v0.x * n0;
        ay += v0.y * n0;
    }

    if (lane < 32) {
        float2 b = ((const float2*)bmu)[lane];
        ((float2*)out_mu)[(size_t)node * 32 + lane] = make_float2(ax + b.x, ay + b.y);
    } else {
        float2 b = ((const float2*)bls)[lane - 32];
        ((float2*)out_ls)[(size_t)node * 32 + (lane - 32)] = make_float2(ax + b.x, ay + b.y);
    }
}

// ---------------------------------------------------------------- launch
extern "C" void kernel_launch(void* const* d_in, const int* in_sizes, int n_in,
                              void* d_out, int out_size, void* d_ws, size_t ws_size,
                              hipStream_t stream) {
    const float* x   = (const float*)d_in[0];
    const void*  ei  = d_in[1];
    const float* Wmu = (const float*)d_in[2];
    const float* bmu = (const float*)d_in[3];
    const float* Wls = (const float*)d_in[4];
    const float* bls = (const float*)d_in[5];

    const int N = in_sizes[0] / IN_C;
    const int E = in_sizes[1] / 2;

    float* out_mu = (float*)d_out;
    float* out_ls = (float*)d_out + (size_t)N * OC;

    // workspace layout (256B aligned)
    char* w = (char*)d_ws;
    auto align256 = [](size_t v) { return (v + 255) & ~(size_t)255; };
    int*   flag   = (int*)w;                  size_t off = 256;
    int*   cnt    = (int*)(w + off);          off += align256((size_t)N * 4);
    int*   cursor = (int*)(w + off);          off += align256((size_t)N * 4);
    float* dinv   = (float*)(w + off);        off += align256((size_t)N * 4);
    int*   rowptr = (int*)(w + off);          off += align256((size_t)(N + 1) * 4);
    int*   esrc   = (int*)(w + off);          off += align256((size_t)E * 4);
    float* h      = (float*)(w + off);        off += align256((size_t)N * HC * 4);

    int n_scan = E < 4096 ? E : 4096;
    hipLaunchKernelGGL(k_detect, dim3(1), dim3(256), 0, stream, ei, n_scan, (long long)N, flag);

    int gN = (N + 255) / 256;
    hipLaunchKernelGGL(k_zero, dim3(gN), dim3(256), 0, stream, cnt, cursor, N);

    int gE4 = (E + 1023) / 1024;
    hipLaunchKernelGGL(k_count, dim3(gE4), dim3(256), 0, stream, ei, cnt, E, flag);

    hipLaunchKernelGGL(k_scan, dim3(1), dim3(1024), 0, stream, cnt, rowptr, N);
    hipLaunchKernelGGL(k_dinv, dim3(gN), dim3(256), 0, stream, cnt, dinv, N);
    hipLaunchKernelGGL(k_fill, dim3(gE4), dim3(256), 0, stream, ei, rowptr, cursor, esrc, E, flag);

    int gG = (N + BR2 - 1) / BR2;
    hipLaunchKernelGGL(k_gemm, dim3(gG), dim3(256), 0, stream, x, Wmu, Wls, h, N);

    int gO = (N + 3) / 4;
    hipLaunchKernelGGL(k_out, dim3(gO), dim3(256), 0, stream, h, rowptr, esrc, dinv, bmu, bls, out_mu, out_ls, N);
}

// Round 9
// 921.499 us; speedup vs baseline: 1.1066x; 1.1066x over previous
//
#include <hip/hip_runtime.h>
#include <hip/hip_bf16.h>

// GCN-VAE encoder: mu = S(xW_mu)+b_mu, logstd = S(xW_ls)+b_ls
// S = D^-1/2 (A+I) D^-1/2  (in-degree by dst, self-loops included)
//
// R5 measured: total 908us (k_out 228, rest 680). R7 (gemm v2 + vectorized
// count/fill) measured 1020us: REGRESSION +112. R8/9: revert gemm to R5's v1,
// keep vectorized count/fill -> dual A/B: vs R7 isolates gemm v2, vs R5
// isolates build vectorization. k_out untouched (fetch-bound floor ~210us).
//
// Pipeline:
//  1. k_detect : int64 vs int32 edge_index (data-driven, graph-capture safe)
//  2. k_zero   : cnt = cursor = 0
//  3. k_count  : cnt[dst]++ (4 edges/thread, vector loads)
//  4. k_scan   : rowptr = exclusive_scan(cnt)  (single-WG 1024-thread scan)
//  5. k_dinv   : dinv[i] = rsqrt(cnt[i]+1)     (+1 = self-loop)
//  6. k_fill   : esrc[rowptr[d] + cursor[d]++] = s   (4 edges/thread loads)
//  7. k_gemm   : h[N][128] = x @ [W_mu | W_ls]  (fp32, 64-row tile = R5 v1)
//  8. k_out    : 1 wave/node: acc = dinv[i]^2*h[i] + sum_e dinv[s]dinv[i]*h[s]

#define IN_C 256
#define HC   128   // concatenated output channels (64 mu + 64 ls)
#define OC   64

// ---------------------------------------------------------------- detect
__global__ void k_detect(const void* ei, int n_scan, long long nn, int* flag) {
    __shared__ int bad;
    if (threadIdx.x == 0) bad = 0;
    __syncthreads();
    const long long* p = (const long long*)ei;
    for (int i = threadIdx.x; i < n_scan; i += blockDim.x) {
        long long v = p[i];
        if (v < 0 || v >= nn) bad = 1;   // benign race
    }
    __syncthreads();
    if (threadIdx.x == 0) *flag = bad;   // 1 => data is int32, 0 => int64
}

// ---------------------------------------------------------------- zero
__global__ __launch_bounds__(256) void k_zero(int* cnt, int* cursor, int n) {
    int i = blockIdx.x * 256 + threadIdx.x;
    if (i < n) { cnt[i] = 0; cursor[i] = 0; }
}

// ---------------------------------------------------------------- count in-degree
// 4 edges per thread, vectorized loads of the dst half.
__global__ __launch_bounds__(256) void k_count(const void* ei, int* cnt, int E, const int* flag) {
    int e0 = (blockIdx.x * 256 + threadIdx.x) * 4;
    if (e0 >= E) return;
    if (e0 + 3 < E) {
        int d[4];
        if (*flag) {
            int4 v = *(const int4*)((const int*)ei + (size_t)E + e0);
            d[0] = v.x; d[1] = v.y; d[2] = v.z; d[3] = v.w;
        } else {
            const long long* p = (const long long*)ei + (size_t)E + e0;
            longlong2 a = *(const longlong2*)p;
            longlong2 b = *(const longlong2*)(p + 2);
            d[0] = (int)a.x; d[1] = (int)a.y; d[2] = (int)b.x; d[3] = (int)b.y;
        }
        #pragma unroll
        for (int u = 0; u < 4; ++u) atomicAdd(&cnt[d[u]], 1);
    } else {
        for (int e = e0; e < E; ++e) {
            int d = (*flag) ? ((const int*)ei)[(size_t)E + e]
                            : (int)((const long long*)ei)[(size_t)E + e];
            atomicAdd(&cnt[d], 1);
        }
    }
}

// ---------------------------------------------------------------- exclusive scan
// Single workgroup, 1024 threads, each owns a contiguous chunk of ~n/1024.
__global__ void k_scan(const int* __restrict__ cnt, int* __restrict__ rowptr, int n) {
    __shared__ int part[1024];
    const int tid = threadIdx.x;
    const int per = (n + 1023) >> 10;
    const int lo  = tid * per;
    const int hi  = min(lo + per, n);
    int s = 0;
    for (int i = lo; i < hi; ++i) s += cnt[i];
    part[tid] = s;
    __syncthreads();
    for (int off = 1; off < 1024; off <<= 1) {   // inclusive Hillis-Steele
        int v = (tid >= off) ? part[tid - off] : 0;
        __syncthreads();
        part[tid] += v;
        __syncthreads();
    }
    int run = (tid > 0) ? part[tid - 1] : 0;     // exclusive base for my chunk
    for (int i = lo; i < hi; ++i) { rowptr[i] = run; run += cnt[i]; }
    if (hi == n) rowptr[n] = run;                // total (benign multi-write)
}

// ---------------------------------------------------------------- dinv
__global__ __launch_bounds__(256) void k_dinv(const int* __restrict__ cnt, float* dinv, int n) {
    int i = blockIdx.x * 256 + threadIdx.x;
    if (i < n) dinv[i] = rsqrtf((float)(cnt[i] + 1));
}

// ---------------------------------------------------------------- CSR fill
// 4 edges per thread, vectorized loads of src and dst halves.
__global__ __launch_bounds__(256) void k_fill(const void* ei, const int* __restrict__ rowptr,
                                              int* cursor, int* __restrict__ esrc,
                                              int E, const int* flag) {
    int e0 = (blockIdx.x * 256 + threadIdx.x) * 4;
    if (e0 >= E) return;
    if (e0 + 3 < E) {
        int s[4], d[4];
        if (*flag) {
            int4 vs = *(const int4*)((const int*)ei + e0);
            int4 vd = *(const int4*)((const int*)ei + (size_t)E + e0);
            s[0] = vs.x; s[1] = vs.y; s[2] = vs.z; s[3] = vs.w;
            d[0] = vd.x; d[1] = vd.y; d[2] = vd.z; d[3] = vd.w;
        } else {
            const long long* ps = (const long long*)ei + e0;
            const long long* pd = (const long long*)ei + (size_t)E + e0;
            longlong2 a = *(const longlong2*)ps;
            longlong2 b = *(const longlong2*)(ps + 2);
            longlong2 c = *(const longlong2*)pd;
            longlong2 g = *(const longlong2*)(pd + 2);
            s[0] = (int)a.x; s[1] = (int)a.y; s[2] = (int)b.x; s[3] = (int)b.y;
            d[0] = (int)c.x; d[1] = (int)c.y; d[2] = (int)g.x; d[3] = (int)g.y;
        }
        #pragma unroll
        for (int u = 0; u < 4; ++u) {
            int pos = rowptr[d[u]] + atomicAdd(&cursor[d[u]], 1);
            esrc[pos] = s[u];
        }
    } else {
        for (int e = e0; e < E; ++e) {
            int s, d;
            if (*flag) {
                s = ((const int*)ei)[e]; d = ((const int*)ei)[(size_t)E + e];
            } else {
                s = (int)((const long long*)ei)[e]; d = (int)((const long long*)ei)[(size_t)E + e];
            }
            int pos = rowptr[d] + atomicAdd(&cursor[d], 1);
            esrc[pos] = s;
        }
    }
}

// ---------------------------------------------------------------- GEMM (R5 v1)
// h[N][128] = x[N][256] @ [W_mu | W_ls][256][128]
// Block: 256 threads, tile 64 rows x 128 ch, thread-tile 4 rows x 8 ch.
#define BR 64
#define KC 32
__global__ __launch_bounds__(256) void k_gemm(const float* __restrict__ x,
                                              const float* __restrict__ Wmu,
                                              const float* __restrict__ Wls,
                                              float* __restrict__ hout, int nrows) {
    __shared__ float xs[BR][KC + 4];     // +4 pad keeps 16B alignment, breaks stride
    __shared__ float wsm[KC][HC];
    const int tid  = threadIdx.x;
    const int trow = tid >> 4;           // 0..15
    const int tcol = tid & 15;           // 0..15
    const int r0   = trow * 4;
    const int c0   = tcol * 4;           // channels c0..c0+3 and c0+64..c0+67
    const size_t rowbase = (size_t)blockIdx.x * BR;

    float acc[4][8];
    #pragma unroll
    for (int i = 0; i < 4; ++i)
        #pragma unroll
        for (int j = 0; j < 8; ++j) acc[i][j] = 0.0f;

    for (int kc = 0; kc < IN_C; kc += KC) {
        __syncthreads();
        // stage x tile: 64 rows x 32 k  (each thread 2 float4s, coalesced)
        {
            int lr = tid >> 3, lk = (tid & 7) * 4;
            #pragma unroll
            for (int half = 0; half < 2; ++half) {
                size_t gr = rowbase + lr + half * 32;
                float4 v = make_float4(0.f, 0.f, 0.f, 0.f);
                if (gr < (size_t)nrows)
                    v = *(const float4*)(x + gr * IN_C + kc + lk);
                *(float4*)&xs[lr + half * 32][lk] = v;
            }
        }
        // stage W chunk: 32 k x 128 ch (each thread 4 float4s)
        #pragma unroll
        for (int i = 0; i < 4; ++i) {
            int q  = tid + 256 * i;          // float4 index 0..1023
            int k  = q >> 5;                 // 32 float4 per k-row
            int cq = (q & 31) * 4;
            const float* srcw = (cq < OC) ? (Wmu + (size_t)(kc + k) * OC + cq)
                                          : (Wls + (size_t)(kc + k) * OC + (cq - OC));
            *(float4*)&wsm[k][cq] = *(const float4*)srcw;
        }
        __syncthreads();

        #pragma unroll 8
        for (int k = 0; k < KC; ++k) {
            float4 w0 = *(const float4*)&wsm[k][c0];
            float4 w1 = *(const float4*)&wsm[k][c0 + OC];
            float xv[4];
            #pragma unroll
            for (int i = 0; i < 4; ++i) xv[i] = xs[r0 + i][k];
            #pragma unroll
            for (int i = 0; i < 4; ++i) {
                acc[i][0] += xv[i] * w0.x; acc[i][1] += xv[i] * w0.y;
                acc[i][2] += xv[i] * w0.z; acc[i][3] += xv[i] * w0.w;
                acc[i][4] += xv[i] * w1.x; acc[i][5] += xv[i] * w1.y;
                acc[i][6] += xv[i] * w1.z; acc[i][7] += xv[i] * w1.w;
            }
        }
    }
    #pragma unroll
    for (int i = 0; i < 4; ++i) {
        size_t gr = rowbase + r0 + i;
        if (gr < (size_t)nrows) {
            *(float4*)(hout + gr * HC + c0)      = make_float4(acc[i][0], acc[i][1], acc[i][2], acc[i][3]);
            *(float4*)(hout + gr * HC + OC + c0) = make_float4(acc[i][4], acc[i][5], acc[i][6], acc[i][7]);
        }
    }
}

// ---------------------------------------------------------------- per-node gather
// One wave (64 lanes) per node; lane owns channels 2*lane, 2*lane+1 (float2).
// 8-deep gather unroll for MLP (mean degree = E/N = 32).
__global__ __launch_bounds__(256) void k_out(const float* __restrict__ h,
                                             const int* __restrict__ rowptr,
                                             const int* __restrict__ esrc,
                                             const float* __restrict__ dinv,
                                             const float* __restrict__ bmu,
                                             const float* __restrict__ bls,
                                             float* __restrict__ out_mu,
                                             float* __restrict__ out_ls, int n) {
    int node = blockIdx.x * 4 + (threadIdx.x >> 6);
    if (node >= n) return;
    int lane = threadIdx.x & 63;
    const float2* __restrict__ h2 = (const float2*)h;

    float di = dinv[node];
    float2 self = h2[(size_t)node * 64 + lane];
    float w  = di * di;
    float ax = self.x * w, ay = self.y * w;

    int k   = rowptr[node];
    int end = rowptr[node + 1];

    for (; k + 7 < end; k += 8) {
        int   s[8];
        float nm[8];
        float2 v[8];
        #pragma unroll
        for (int u = 0; u < 8; ++u) s[u] = esrc[k + u];
        #pragma unroll
        for (int u = 0; u < 8; ++u) nm[u] = dinv[s[u]] * di;
        #pragma unroll
        for (int u = 0; u < 8; ++u) v[u] = h2[(size_t)s[u] * 64 + lane];
        #pragma unroll
        for (int u = 0; u < 8; ++u) { ax += v[u].x * nm[u]; ay += v[u].y * nm[u]; }
    }
    for (; k < end; ++k) {
        int s0 = esrc[k];
        float n0 = dinv[s0] * di;
        float2 v0 = h2[(size_t)s0 * 64 + lane];
        ax += v0.x * n0;
        ay += v0.y * n0;
    }

    if (lane < 32) {
        float2 b = ((const float2*)bmu)[lane];
        ((float2*)out_mu)[(size_t)node * 32 + lane] = make_float2(ax + b.x, ay + b.y);
    } else {
        float2 b = ((const float2*)bls)[lane - 32];
        ((float2*)out_ls)[(size_t)node * 32 + (lane - 32)] = make_float2(ax + b.x, ay + b.y);
    }
}

// ---------------------------------------------------------------- launch
extern "C" void kernel_launch(void* const* d_in, const int* in_sizes, int n_in,
                              void* d_out, int out_size, void* d_ws, size_t ws_size,
                              hipStream_t stream) {
    const float* x   = (const float*)d_in[0];
    const void*  ei  = d_in[1];
    const float* Wmu = (const float*)d_in[2];
    const float* bmu = (const float*)d_in[3];
    const float* Wls = (const float*)d_in[4];
    const float* bls = (const float*)d_in[5];

    const int N = in_sizes[0] / IN_C;
    const int E = in_sizes[1] / 2;

    float* out_mu = (float*)d_out;
    float* out_ls = (float*)d_out + (size_t)N * OC;

    // workspace layout (256B aligned)
    char* w = (char*)d_ws;
    auto align256 = [](size_t v) { return (v + 255) & ~(size_t)255; };
    int*   flag   = (int*)w;                  size_t off = 256;
    int*   cnt    = (int*)(w + off);          off += align256((size_t)N * 4);
    int*   cursor = (int*)(w + off);          off += align256((size_t)N * 4);
    float* dinv   = (float*)(w + off);        off += align256((size_t)N * 4);
    int*   rowptr = (int*)(w + off);          off += align256((size_t)(N + 1) * 4);
    int*   esrc   = (int*)(w + off);          off += align256((size_t)E * 4);
    float* h      = (float*)(w + off);        off += align256((size_t)N * HC * 4);

    int n_scan = E < 4096 ? E : 4096;
    hipLaunchKernelGGL(k_detect, dim3(1), dim3(256), 0, stream, ei, n_scan, (long long)N, flag);

    int gN = (N + 255) / 256;
    hipLaunchKernelGGL(k_zero, dim3(gN), dim3(256), 0, stream, cnt, cursor, N);

    int gE4 = (E + 1023) / 1024;
    hipLaunchKernelGGL(k_count, dim3(gE4), dim3(256), 0, stream, ei, cnt, E, flag);

    hipLaunchKernelGGL(k_scan, dim3(1), dim3(1024), 0, stream, cnt, rowptr, N);
    hipLaunchKernelGGL(k_dinv, dim3(gN), dim3(256), 0, stream, cnt, dinv, N);
    hipLaunchKernelGGL(k_fill, dim3(gE4), dim3(256), 0, stream, ei, rowptr, cursor, esrc, E, flag);

    int gG = (N + BR - 1) / BR;
    hipLaunchKernelGGL(k_gemm, dim3(gG), dim3(256), 0, stream, x, Wmu, Wls, h, N);

    int gO = (N + 3) / 4;
    hipLaunchKernelGGL(k_out, dim3(gO), dim3(256), 0, stream, h, rowptr, esrc, dinv, bmu, bls, out_mu, out_ls, N);
}

// Round 10
// 908.619 us; speedup vs baseline: 1.1223x; 1.0142x over previous
//
#include <hip/hip_runtime.h>
#include <hip/hip_bf16.h>

// GCN-VAE encoder: mu = S(xW_mu)+b_mu, logstd = S(xW_ls)+b_ls
// S = D^-1/2 (A+I) D^-1/2  (in-degree by dst, self-loops included)
//
// Measured history: R2 atomic-scatter 5794us (WRITE 6.4GB). R5 CSR-gather
// 908us (k_out 228 top, WRITE 50MB). R7 gemm-v2+vec-build 1020us. R9 dual-A/B:
// gemm v2 = -99us regression (reverted); vec build = neutral (kept).
// R10: single lever = k_gemm -> MFMA bf16 3-term split (hi*Whi+hi*Wlo+lo*Whi),
// 128x128 tile, 4 waves x (2 row-tiles x 8 col-tiles) 16x16x32 MFMA,
// LDS pitch-40 bf16 (16B-aligned b128 frags, <=2-way banks). Rest untouched.
//
// Pipeline:
//  1. k_detect : int64 vs int32 edge_index (data-driven, graph-capture safe)
//  2. k_zero   : cnt = cursor = 0
//  3. k_count  : cnt[dst]++ (4 edges/thread, vector loads)
//  4. k_scan   : rowptr = exclusive_scan(cnt)  (single-WG 1024-thread scan)
//  5. k_dinv   : dinv[i] = rsqrt(cnt[i]+1)     (+1 = self-loop)
//  6. k_fill   : esrc[rowptr[d] + cursor[d]++] = s
//  7. k_gemm   : h[N][128] = x @ [W_mu | W_ls]  (MFMA split-bf16)
//  8. k_out    : 1 wave/node: acc = dinv[i]^2*h[i] + sum_e dinv[s]dinv[i]*h[s]

#define IN_C 256
#define HC   128   // concatenated output channels (64 mu + 64 ls)
#define OC   64

typedef __attribute__((ext_vector_type(8))) short bf16x8;
typedef __attribute__((ext_vector_type(4))) float f32x4;

__device__ __forceinline__ short f2bf(float f) {
    union { float f; unsigned u; } v; v.f = f;
    unsigned r = v.u + 0x7fffu + ((v.u >> 16) & 1u);   // RNE
    return (short)(r >> 16);
}
__device__ __forceinline__ float bf2f(short s) {
    union { float f; unsigned u; } v; v.u = ((unsigned)(unsigned short)s) << 16;
    return v.f;
}

// ---------------------------------------------------------------- detect
__global__ void k_detect(const void* ei, int n_scan, long long nn, int* flag) {
    __shared__ int bad;
    if (threadIdx.x == 0) bad = 0;
    __syncthreads();
    const long long* p = (const long long*)ei;
    for (int i = threadIdx.x; i < n_scan; i += blockDim.x) {
        long long v = p[i];
        if (v < 0 || v >= nn) bad = 1;   // benign race
    }
    __syncthreads();
    if (threadIdx.x == 0) *flag = bad;   // 1 => data is int32, 0 => int64
}

// ---------------------------------------------------------------- zero
__global__ __launch_bounds__(256) void k_zero(int* cnt, int* cursor, int n) {
    int i = blockIdx.x * 256 + threadIdx.x;
    if (i < n) { cnt[i] = 0; cursor[i] = 0; }
}

// ---------------------------------------------------------------- count in-degree
__global__ __launch_bounds__(256) void k_count(const void* ei, int* cnt, int E, const int* flag) {
    int e0 = (blockIdx.x * 256 + threadIdx.x) * 4;
    if (e0 >= E) return;
    if (e0 + 3 < E) {
        int d[4];
        if (*flag) {
            int4 v = *(const int4*)((const int*)ei + (size_t)E + e0);
            d[0] = v.x; d[1] = v.y; d[2] = v.z; d[3] = v.w;
        } else {
            const long long* p = (const long long*)ei + (size_t)E + e0;
            longlong2 a = *(const longlong2*)p;
            longlong2 b = *(const longlong2*)(p + 2);
            d[0] = (int)a.x; d[1] = (int)a.y; d[2] = (int)b.x; d[3] = (int)b.y;
        }
        #pragma unroll
        for (int u = 0; u < 4; ++u) atomicAdd(&cnt[d[u]], 1);
    } else {
        for (int e = e0; e < E; ++e) {
            int d = (*flag) ? ((const int*)ei)[(size_t)E + e]
                            : (int)((const long long*)ei)[(size_t)E + e];
            atomicAdd(&cnt[d], 1);
        }
    }
}

// ---------------------------------------------------------------- exclusive scan
__global__ void k_scan(const int* __restrict__ cnt, int* __restrict__ rowptr, int n) {
    __shared__ int part[1024];
    const int tid = threadIdx.x;
    const int per = (n + 1023) >> 10;
    const int lo  = tid * per;
    const int hi  = min(lo + per, n);
    int s = 0;
    for (int i = lo; i < hi; ++i) s += cnt[i];
    part[tid] = s;
    __syncthreads();
    for (int off = 1; off < 1024; off <<= 1) {
        int v = (tid >= off) ? part[tid - off] : 0;
        __syncthreads();
        part[tid] += v;
        __syncthreads();
    }
    int run = (tid > 0) ? part[tid - 1] : 0;
    for (int i = lo; i < hi; ++i) { rowptr[i] = run; run += cnt[i]; }
    if (hi == n) rowptr[n] = run;
}

// ---------------------------------------------------------------- dinv
__global__ __launch_bounds__(256) void k_dinv(const int* __restrict__ cnt, float* dinv, int n) {
    int i = blockIdx.x * 256 + threadIdx.x;
    if (i < n) dinv[i] = rsqrtf((float)(cnt[i] + 1));
}

// ---------------------------------------------------------------- CSR fill
__global__ __launch_bounds__(256) void k_fill(const void* ei, const int* __restrict__ rowptr,
                                              int* cursor, int* __restrict__ esrc,
                                              int E, const int* flag) {
    int e0 = (blockIdx.x * 256 + threadIdx.x) * 4;
    if (e0 >= E) return;
    if (e0 + 3 < E) {
        int s[4], d[4];
        if (*flag) {
            int4 vs = *(const int4*)((const int*)ei + e0);
            int4 vd = *(const int4*)((const int*)ei + (size_t)E + e0);
            s[0] = vs.x; s[1] = vs.y; s[2] = vs.z; s[3] = vs.w;
            d[0] = vd.x; d[1] = vd.y; d[2] = vd.z; d[3] = vd.w;
        } else {
            const long long* ps = (const long long*)ei + e0;
            const long long* pd = (const long long*)ei + (size_t)E + e0;
            longlong2 a = *(const longlong2*)ps;
            longlong2 b = *(const longlong2*)(ps + 2);
            longlong2 c = *(const longlong2*)pd;
            longlong2 g = *(const longlong2*)(pd + 2);
            s[0] = (int)a.x; s[1] = (int)a.y; s[2] = (int)b.x; s[3] = (int)b.y;
            d[0] = (int)c.x; d[1] = (int)c.y; d[2] = (int)g.x; d[3] = (int)g.y;
        }
        #pragma unroll
        for (int u = 0; u < 4; ++u) {
            int pos = rowptr[d[u]] + atomicAdd(&cursor[d[u]], 1);
            esrc[pos] = s[u];
        }
    } else {
        for (int e = e0; e < E; ++e) {
            int s, d;
            if (*flag) {
                s = ((const int*)ei)[e]; d = ((const int*)ei)[(size_t)E + e];
            } else {
                s = (int)((const long long*)ei)[e]; d = (int)((const long long*)ei)[(size_t)E + e];
            }
            int pos = rowptr[d] + atomicAdd(&cursor[d], 1);
            esrc[pos] = s;
        }
    }
}

// ---------------------------------------------------------------- GEMM (MFMA v3)
// h[N][128] = x[N][256] @ [W_mu | W_ls][256][128], split-bf16 3-term.
// 128x128 block tile, 4 waves; wave = 2 row-tiles x 8 col-tiles of 16x16x32.
// LDS pitch 40 bf16 (80B): 16B-aligned b128 fragments, <=2-way bank aliasing.
// A: row=lane&15, k=(lane>>4)*8+[0,8). B^T: col=lane&15, same k.
// C/D: col=lane&15, row=(lane>>4)*4+reg  (guide m89, dtype-independent).
#define GP 40
__global__ __launch_bounds__(256) void k_gemm(const float* __restrict__ x,
                                              const float* __restrict__ Wmu,
                                              const float* __restrict__ Wls,
                                              float* __restrict__ hout, int nrows) {
    __shared__ short Ah[128][GP], Al[128][GP];
    __shared__ short Bh[128][GP], Bl[128][GP];
    const int tid  = threadIdx.x;
    const int wid  = tid >> 6;
    const int lane = tid & 63;
    const int l15  = lane & 15;
    const int k0   = (lane >> 4) * 8;
    const size_t rowbase = (size_t)blockIdx.x * 128;

    f32x4 acc[2][8];
    #pragma unroll
    for (int rt = 0; rt < 2; ++rt)
        #pragma unroll
        for (int ct = 0; ct < 8; ++ct) acc[rt][ct] = (f32x4){0.f, 0.f, 0.f, 0.f};

    for (int kc = 0; kc < IN_C; kc += 32) {
        __syncthreads();
        // stage A: 128 rows x 32 k, fp32 -> hi/lo bf16 (1024 float4 / 256 thr)
        #pragma unroll
        for (int it = 0; it < 4; ++it) {
            int q = tid + 256 * it;
            int r = q >> 3, f = q & 7;           // f*4 = k offset
            size_t gr = rowbase + r;
            float4 v = make_float4(0.f, 0.f, 0.f, 0.f);
            if (gr < (size_t)nrows)
                v = *(const float4*)(x + gr * IN_C + kc + f * 4);
            short h0 = f2bf(v.x), h1 = f2bf(v.y), h2 = f2bf(v.z), h3 = f2bf(v.w);
            short l0 = f2bf(v.x - bf2f(h0)), l1 = f2bf(v.y - bf2f(h1));
            short l2 = f2bf(v.z - bf2f(h2)), l3 = f2bf(v.w - bf2f(h3));
            *(ushort4*)&Ah[r][f * 4] = make_ushort4((unsigned short)h0, (unsigned short)h1,
                                                    (unsigned short)h2, (unsigned short)h3);
            *(ushort4*)&Al[r][f * 4] = make_ushort4((unsigned short)l0, (unsigned short)l1,
                                                    (unsigned short)l2, (unsigned short)l3);
        }
        // stage B^T: 128 cols x 32 k. Column-wise reads of L2-resident W so the
        // LDS writes are k-contiguous b128. (512 tasks / 256 thr)
        #pragma unroll
        for (int it = 0; it < 2; ++it) {
            int q = tid + 256 * it;
            int c = q >> 2, g = q & 3;           // k-group g*8
            const float* wc = (c < OC) ? (Wmu + c) : (Wls + (c - OC));
            short hb[8], lb[8];
            #pragma unroll
            for (int j = 0; j < 8; ++j) {
                float v = wc[(size_t)(kc + g * 8 + j) * OC];
                short h = f2bf(v);
                hb[j] = h;
                lb[j] = f2bf(v - bf2f(h));
            }
            *(bf16x8*)&Bh[c][g * 8] = *(bf16x8*)hb;
            *(bf16x8*)&Bl[c][g * 8] = *(bf16x8*)lb;
        }
        __syncthreads();

        bf16x8 ah[2], al[2];
        #pragma unroll
        for (int rt = 0; rt < 2; ++rt) {
            int r = rt * 64 + wid * 16 + l15;
            ah[rt] = *(bf16x8*)&Ah[r][k0];
            al[rt] = *(bf16x8*)&Al[r][k0];
        }
        #pragma unroll
        for (int ct = 0; ct < 8; ++ct) {
            bf16x8 bh = *(bf16x8*)&Bh[ct * 16 + l15][k0];
            bf16x8 bl = *(bf16x8*)&Bl[ct * 16 + l15][k0];
            #pragma unroll
            for (int rt = 0; rt < 2; ++rt) {
                acc[rt][ct] = __builtin_amdgcn_mfma_f32_16x16x32_bf16(al[rt], bh, acc[rt][ct], 0, 0, 0);
                acc[rt][ct] = __builtin_amdgcn_mfma_f32_16x16x32_bf16(ah[rt], bl, acc[rt][ct], 0, 0, 0);
                acc[rt][ct] = __builtin_amdgcn_mfma_f32_16x16x32_bf16(ah[rt], bh, acc[rt][ct], 0, 0, 0);
            }
        }
    }

    const int orow = (lane >> 4) * 4;
    #pragma unroll
    for (int rt = 0; rt < 2; ++rt)
        #pragma unroll
        for (int ct = 0; ct < 8; ++ct)
            #pragma unroll
            for (int rg = 0; rg < 4; ++rg) {
                size_t grow = rowbase + rt * 64 + wid * 16 + orow + rg;
                if (grow < (size_t)nrows)
                    hout[grow * HC + ct * 16 + l15] = acc[rt][ct][rg];
            }
}

// ---------------------------------------------------------------- per-node gather
// One wave (64 lanes) per node; lane owns channels 2*lane, 2*lane+1 (float2).
__global__ __launch_bounds__(256) void k_out(const float* __restrict__ h,
                                             const int* __restrict__ rowptr,
                                             const int* __restrict__ esrc,
                                             const float* __restrict__ dinv,
                                             const float* __restrict__ bmu,
                                             const float* __restrict__ bls,
                                             float* __restrict__ out_mu,
                                             float* __restrict__ out_ls, int n) {
    int node = blockIdx.x * 4 + (threadIdx.x >> 6);
    if (node >= n) return;
    int lane = threadIdx.x & 63;
    const float2* __restrict__ h2 = (const float2*)h;

    float di = dinv[node];
    float2 self = h2[(size_t)node * 64 + lane];
    float w  = di * di;
    float ax = self.x * w, ay = self.y * w;

    int k   = rowptr[node];
    int end = rowptr[node + 1];

    for (; k + 7 < end; k += 8) {
        int   s[8];
        float nm[8];
        float2 v[8];
        #pragma unroll
        for (int u = 0; u < 8; ++u) s[u] = esrc[k + u];
        #pragma unroll
        for (int u = 0; u < 8; ++u) nm[u] = dinv[s[u]] * di;
        #pragma unroll
        for (int u = 0; u < 8; ++u) v[u] = h2[(size_t)s[u] * 64 + lane];
        #pragma unroll
        for (int u = 0; u < 8; ++u) { ax += v[u].x * nm[u]; ay += v[u].y * nm[u]; }
    }
    for (; k < end; ++k) {
        int s0 = esrc[k];
        float n0 = dinv[s0] * di;
        float2 v0 = h2[(size_t)s0 * 64 + lane];
        ax += v0.x * n0;
        ay += v0.y * n0;
    }

    if (lane < 32) {
        float2 b = ((const float2*)bmu)[lane];
        ((float2*)out_mu)[(size_t)node * 32 + lane] = make_float2(ax + b.x, ay + b.y);
    } else {
        float2 b = ((const float2*)bls)[lane - 32];
        ((float2*)out_ls)[(size_t)node * 32 + (lane - 32)] = make_float2(ax + b.x, ay + b.y);
    }
}

// ---------------------------------------------------------------- launch
extern "C" void kernel_launch(void* const* d_in, const int* in_sizes, int n_in,
                              void* d_out, int out_size, void* d_ws, size_t ws_size,
                              hipStream_t stream) {
    const float* x   = (const float*)d_in[0];
    const void*  ei  = d_in[1];
    const float* Wmu = (const float*)d_in[2];
    const float* bmu = (const float*)d_in[3];
    const float* Wls = (const float*)d_in[4];
    const float* bls = (const float*)d_in[5];

    const int N = in_sizes[0] / IN_C;
    const int E = in_sizes[1] / 2;

    float* out_mu = (float*)d_out;
    float* out_ls = (float*)d_out + (size_t)N * OC;

    // workspace layout (256B aligned)
    char* w = (char*)d_ws;
    auto align256 = [](size_t v) { return (v + 255) & ~(size_t)255; };
    int*   flag   = (int*)w;                  size_t off = 256;
    int*   cnt    = (int*)(w + off);          off += align256((size_t)N * 4);
    int*   cursor = (int*)(w + off);          off += align256((size_t)N * 4);
    float* dinv   = (float*)(w + off);        off += align256((size_t)N * 4);
    int*   rowptr = (int*)(w + off);          off += align256((size_t)(N + 1) * 4);
    int*   esrc   = (int*)(w + off);          off += align256((size_t)E * 4);
    float* h      = (float*)(w + off);        off += align256((size_t)N * HC * 4);

    int n_scan = E < 4096 ? E : 4096;
    hipLaunchKernelGGL(k_detect, dim3(1), dim3(256), 0, stream, ei, n_scan, (long long)N, flag);

    int gN = (N + 255) / 256;
    hipLaunchKernelGGL(k_zero, dim3(gN), dim3(256), 0, stream, cnt, cursor, N);

    int gE4 = (E + 1023) / 1024;
    hipLaunchKernelGGL(k_count, dim3(gE4), dim3(256), 0, stream, ei, cnt, E, flag);

    hipLaunchKernelGGL(k_scan, dim3(1), dim3(1024), 0, stream, cnt, rowptr, N);
    hipLaunchKernelGGL(k_dinv, dim3(gN), dim3(256), 0, stream, cnt, dinv, N);
    hipLaunchKernelGGL(k_fill, dim3(gE4), dim3(256), 0, stream, ei, rowptr, cursor, esrc, E, flag);

    int gG = (N + 127) / 128;
    hipLaunchKernelGGL(k_gemm, dim3(gG), dim3(256), 0, stream, x, Wmu, Wls, h, N);

    int gO = (N + 3) / 4;
    hipLaunchKernelGGL(k_out, dim3(gO), dim3(256), 0, stream, h, rowptr, esrc, dinv, bmu, bls, out_mu, out_ls, N);
}

// Round 12
// 758.831 us; speedup vs baseline: 1.3439x; 1.1974x over previous
//
#include <hip/hip_runtime.h>
#include <hip/hip_bf16.h>

// GCN-VAE encoder: mu = S(xW_mu)+b_mu, logstd = S(xW_ls)+b_ls
// S = D^-1/2 (A+I) D^-1/2  (in-degree by dst, self-loops included)
//
// Measured: R2 atomic 5794 | R5 CSR 908 | R7 gemm-v2 1020 (regr) | R9 921 |
// R10 MFMA-gemm 908 (gemm v1~=MFMA, gemm small). k_out 228 is the only
// visible kernel; ~500us hidden below 227. R11/12: (a) multi-block scan (old
// single-WG scan = prime suspect), (b) k_out 2-edges/iter float4 + shfl_xor
// combine (halves gather instructions; tests latency-bound hypothesis).
//
// Pipeline:
//  1. k_detect : int64 vs int32 edge_index
//  2. k_zero   : cnt = 0
//  3. k_count  : cnt[dst]++ (4 edges/thread)
//  4. k_scan1  : bsum[b] = sum of block's 4096 cnt
//  5. k_scan2  : bbase = serial exclusive scan of bsum (1 thread, <=64 vals)
//  6. k_scan3  : rowptr + dinv=rsqrt(cnt+1) + cursor=0 (fused)
//  7. k_fill   : esrc[rowptr[d] + cursor[d]++] = s
//  8. k_gemm   : h[N][128] = x @ [W_mu | W_ls]  (MFMA split-bf16, R10)
//  9. k_out    : 1 wave/node, 2 edges/iter, float4/lane, shfl_xor(32) combine

#define IN_C 256
#define HC   128
#define OC   64
#define SCHUNK 4096   // scan elements per block (256 thr x 16)

typedef __attribute__((ext_vector_type(8))) short bf16x8;
typedef __attribute__((ext_vector_type(4))) float f32x4;

__device__ __forceinline__ short f2bf(float f) {
    union { float f; unsigned u; } v; v.f = f;
    unsigned r = v.u + 0x7fffu + ((v.u >> 16) & 1u);   // RNE
    return (short)(r >> 16);
}
__device__ __forceinline__ float bf2f(short s) {
    union { float f; unsigned u; } v; v.u = ((unsigned)(unsigned short)s) << 16;
    return v.f;
}

// ---------------------------------------------------------------- detect
__global__ void k_detect(const void* ei, int n_scan, long long nn, int* flag) {
    __shared__ int bad;
    if (threadIdx.x == 0) bad = 0;
    __syncthreads();
    const long long* p = (const long long*)ei;
    for (int i = threadIdx.x; i < n_scan; i += blockDim.x) {
        long long v = p[i];
        if (v < 0 || v >= nn) bad = 1;
    }
    __syncthreads();
    if (threadIdx.x == 0) *flag = bad;   // 1 => int32 data, 0 => int64
}

// ---------------------------------------------------------------- zero cnt
__global__ __launch_bounds__(256) void k_zero(int* cnt, int n) {
    int i = blockIdx.x * 256 + threadIdx.x;
    if (i < n) cnt[i] = 0;
}

// ---------------------------------------------------------------- count
__global__ __launch_bounds__(256) void k_count(const void* ei, int* cnt, int E, const int* flag) {
    int e0 = (blockIdx.x * 256 + threadIdx.x) * 4;
    if (e0 >= E) return;
    if (e0 + 3 < E) {
        int d[4];
        if (*flag) {
            int4 v = *(const int4*)((const int*)ei + (size_t)E + e0);
            d[0] = v.x; d[1] = v.y; d[2] = v.z; d[3] = v.w;
        } else {
            const long long* p = (const long long*)ei + (size_t)E + e0;
            longlong2 a = *(const longlong2*)p;
            longlong2 b = *(const longlong2*)(p + 2);
            d[0] = (int)a.x; d[1] = (int)a.y; d[2] = (int)b.x; d[3] = (int)b.y;
        }
        #pragma unroll
        for (int u = 0; u < 4; ++u) atomicAdd(&cnt[d[u]], 1);
    } else {
        for (int e = e0; e < E; ++e) {
            int d = (*flag) ? ((const int*)ei)[(size_t)E + e]
                            : (int)((const long long*)ei)[(size_t)E + e];
            atomicAdd(&cnt[d], 1);
        }
    }
}

// ---------------------------------------------------------------- scan phase 1
// block b: bsum[b] = sum cnt[b*4096 .. b*4096+4096)
__global__ __launch_bounds__(256) void k_scan1(const int* __restrict__ cnt, int* __restrict__ bsum, int n) {
    __shared__ int red[256];
    const int tid = threadIdx.x;
    int lo = blockIdx.x * SCHUNK + tid * 16;
    int s = 0;
    if (lo < n) {
        int hi = min(lo + 16, n);
        if (hi == lo + 16) {
            #pragma unroll
            for (int q = 0; q < 4; ++q) {
                int4 v = *(const int4*)(cnt + lo + q * 4);
                s += v.x + v.y + v.z + v.w;
            }
        } else {
            for (int i = lo; i < hi; ++i) s += cnt[i];
        }
    }
    red[tid] = s;
    __syncthreads();
    for (int off = 128; off > 0; off >>= 1) {
        if (tid < off) red[tid] += red[tid + off];
        __syncthreads();
    }
    if (tid == 0) bsum[blockIdx.x] = red[0];
}

// ---------------------------------------------------------------- scan phase 2
// exclusive scan of nb (<=64) block sums; serial on thread 0 (L2-resident)
__global__ void k_scan2(const int* __restrict__ bsum, int* __restrict__ bbase, int nb) {
    if (threadIdx.x == 0) {
        int run = 0;
        for (int b = 0; b < nb; ++b) { bbase[b] = run; run += bsum[b]; }
    }
}

// ---------------------------------------------------------------- scan phase 3
// rowptr[i] (exclusive prefix), dinv[i] = rsqrt(cnt[i]+1), cursor[i] = 0
__global__ __launch_bounds__(256) void k_scan3(const int* __restrict__ cnt,
                                               const int* __restrict__ bbase,
                                               int* __restrict__ rowptr,
                                               float* __restrict__ dinv,
                                               int* __restrict__ cursor, int n) {
    __shared__ int part[256];
    const int tid = threadIdx.x;
    int lo = blockIdx.x * SCHUNK + tid * 16;
    int loc[16];
    int s = 0, cntv = 0;
    if (lo < n) {
        cntv = min(lo + 16, n) - lo;
        if (cntv == 16) {
            #pragma unroll
            for (int q = 0; q < 4; ++q) {
                int4 v = *(const int4*)(cnt + lo + q * 4);
                loc[q * 4 + 0] = v.x; loc[q * 4 + 1] = v.y;
                loc[q * 4 + 2] = v.z; loc[q * 4 + 3] = v.w;
            }
        } else {
            for (int u = 0; u < cntv; ++u) loc[u] = cnt[lo + u];
        }
        for (int u = 0; u < cntv; ++u) s += loc[u];
    }
    part[tid] = s;
    __syncthreads();
    for (int off = 1; off < 256; off <<= 1) {      // inclusive Hillis-Steele
        int v = (tid >= off) ? part[tid - off] : 0;
        __syncthreads();
        part[tid] += v;
        __syncthreads();
    }
    if (lo < n) {
        int run = bbase[blockIdx.x] + (tid ? part[tid - 1] : 0);
        for (int u = 0; u < cntv; ++u) {
            rowptr[lo + u] = run;
            dinv[lo + u]   = rsqrtf((float)(loc[u] + 1));
            cursor[lo + u] = 0;
            run += loc[u];
        }
        if (lo + cntv == n) rowptr[n] = run;       // thread ending exactly at n
    }
}

// ---------------------------------------------------------------- CSR fill
__global__ __launch_bounds__(256) void k_fill(const void* ei, const int* __restrict__ rowptr,
                                              int* cursor, int* __restrict__ esrc,
                                              int E, const int* flag) {
    int e0 = (blockIdx.x * 256 + threadIdx.x) * 4;
    if (e0 >= E) return;
    if (e0 + 3 < E) {
        int s[4], d[4];
        if (*flag) {
            int4 vs = *(const int4*)((const int*)ei + e0);
            int4 vd = *(const int4*)((const int*)ei + (size_t)E + e0);
            s[0] = vs.x; s[1] = vs.y; s[2] = vs.z; s[3] = vs.w;
            d[0] = vd.x; d[1] = vd.y; d[2] = vd.z; d[3] = vd.w;
        } else {
            const long long* ps = (const long long*)ei + e0;
            const long long* pd = (const long long*)ei + (size_t)E + e0;
            longlong2 a = *(const longlong2*)ps;
            longlong2 b = *(const longlong2*)(ps + 2);
            longlong2 c = *(const longlong2*)pd;
            longlong2 g = *(const longlong2*)(pd + 2);
            s[0] = (int)a.x; s[1] = (int)a.y; s[2] = (int)b.x; s[3] = (int)b.y;
            d[0] = (int)c.x; d[1] = (int)c.y; d[2] = (int)g.x; d[3] = (int)g.y;
        }
        #pragma unroll
        for (int u = 0; u < 4; ++u) {
            int pos = rowptr[d[u]] + atomicAdd(&cursor[d[u]], 1);
            esrc[pos] = s[u];
        }
    } else {
        for (int e = e0; e < E; ++e) {
            int s, d;
            if (*flag) {
                s = ((const int*)ei)[e]; d = ((const int*)ei)[(size_t)E + e];
            } else {
                s = (int)((const long long*)ei)[e]; d = (int)((const long long*)ei)[(size_t)E + e];
            }
            int pos = rowptr[d] + atomicAdd(&cursor[d], 1);
            esrc[pos] = s;
        }
    }
}

// ---------------------------------------------------------------- GEMM (MFMA, R10)
#define GP 40
__global__ __launch_bounds__(256) void k_gemm(const float* __restrict__ x,
                                              const float* __restrict__ Wmu,
                                              const float* __restrict__ Wls,
                                              float* __restrict__ hout, int nrows) {
    __shared__ short Ah[128][GP], Al[128][GP];
    __shared__ short Bh[128][GP], Bl[128][GP];
    const int tid  = threadIdx.x;
    const int wid  = tid >> 6;
    const int lane = tid & 63;
    const int l15  = lane & 15;
    const int k0   = (lane >> 4) * 8;
    const size_t rowbase = (size_t)blockIdx.x * 128;

    f32x4 acc[2][8];
    #pragma unroll
    for (int rt = 0; rt < 2; ++rt)
        #pragma unroll
        for (int ct = 0; ct < 8; ++ct) acc[rt][ct] = (f32x4){0.f, 0.f, 0.f, 0.f};

    for (int kc = 0; kc < IN_C; kc += 32) {
        __syncthreads();
        #pragma unroll
        for (int it = 0; it < 4; ++it) {
            int q = tid + 256 * it;
            int r = q >> 3, f = q & 7;
            size_t gr = rowbase + r;
            float4 v = make_float4(0.f, 0.f, 0.f, 0.f);
            if (gr < (size_t)nrows)
                v = *(const float4*)(x + gr * IN_C + kc + f * 4);
            short h0 = f2bf(v.x), h1 = f2bf(v.y), h2 = f2bf(v.z), h3 = f2bf(v.w);
            short l0 = f2bf(v.x - bf2f(h0)), l1 = f2bf(v.y - bf2f(h1));
            short l2 = f2bf(v.z - bf2f(h2)), l3 = f2bf(v.w - bf2f(h3));
            *(ushort4*)&Ah[r][f * 4] = make_ushort4((unsigned short)h0, (unsigned short)h1,
                                                    (unsigned short)h2, (unsigned short)h3);
            *(ushort4*)&Al[r][f * 4] = make_ushort4((unsigned short)l0, (unsigned short)l1,
                                                    (unsigned short)l2, (unsigned short)l3);
        }
        #pragma unroll
        for (int it = 0; it < 2; ++it) {
            int q = tid + 256 * it;
            int c = q >> 2, g = q & 3;
            const float* wc = (c < OC) ? (Wmu + c) : (Wls + (c - OC));
            short hb[8], lb[8];
            #pragma unroll
            for (int j = 0; j < 8; ++j) {
                float v = wc[(size_t)(kc + g * 8 + j) * OC];
                short h = f2bf(v);
                hb[j] = h;
                lb[j] = f2bf(v - bf2f(h));
            }
            *(bf16x8*)&Bh[c][g * 8] = *(bf16x8*)hb;
            *(bf16x8*)&Bl[c][g * 8] = *(bf16x8*)lb;
        }
        __syncthreads();

        bf16x8 ah[2], al[2];
        #pragma unroll
        for (int rt = 0; rt < 2; ++rt) {
            int r = rt * 64 + wid * 16 + l15;
            ah[rt] = *(bf16x8*)&Ah[r][k0];
            al[rt] = *(bf16x8*)&Al[r][k0];
        }
        #pragma unroll
        for (int ct = 0; ct < 8; ++ct) {
            bf16x8 bh = *(bf16x8*)&Bh[ct * 16 + l15][k0];
            bf16x8 bl = *(bf16x8*)&Bl[ct * 16 + l15][k0];
            #pragma unroll
            for (int rt = 0; rt < 2; ++rt) {
                acc[rt][ct] = __builtin_amdgcn_mfma_f32_16x16x32_bf16(al[rt], bh, acc[rt][ct], 0, 0, 0);
                acc[rt][ct] = __builtin_amdgcn_mfma_f32_16x16x32_bf16(ah[rt], bl, acc[rt][ct], 0, 0, 0);
                acc[rt][ct] = __builtin_amdgcn_mfma_f32_16x16x32_bf16(ah[rt], bh, acc[rt][ct], 0, 0, 0);
            }
        }
    }

    const int orow = (lane >> 4) * 4;
    #pragma unroll
    for (int rt = 0; rt < 2; ++rt)
        #pragma unroll
        for (int ct = 0; ct < 8; ++ct)
            #pragma unroll
            for (int rg = 0; rg < 4; ++rg) {
                size_t grow = rowbase + rt * 64 + wid * 16 + orow + rg;
                if (grow < (size_t)nrows)
                    hout[grow * HC + ct * 16 + l15] = acc[rt][ct][rg];
            }
}

// ---------------------------------------------------------------- per-node gather v2
// 1 wave/node. Per iteration: lanes 0-31 process edge k (even), lanes 32-63
// edge k+1 (odd); each lane reads one float4 (4 channels) of h[src].
// Halves gather instructions + serial chain vs v1. Final: shfl_xor(32) combine.
__global__ __launch_bounds__(256) void k_out(const float* __restrict__ h,
                                             const int* __restrict__ rowptr,
                                             const int* __restrict__ esrc,
                                             const float* __restrict__ dinv,
                                             const float* __restrict__ bmu,
                                             const float* __restrict__ bls,
                                             float* __restrict__ out_mu,
                                             float* __restrict__ out_ls, int n) {
    int node = blockIdx.x * 4 + (threadIdx.x >> 6);
    if (node >= n) return;
    const int lane = threadIdx.x & 63;
    const int half = lane >> 5;          // 0 = even edges, 1 = odd edges
    const int j    = lane & 31;          // float4 channel group: ch [4j, 4j+4)
    const float4* __restrict__ h4 = (const float4*)h;

    float di = dinv[node];
    float4 acc = make_float4(0.f, 0.f, 0.f, 0.f);
    if (half == 0) {                     // self-loop term on even half only
        float w = di * di;
        float4 self = h4[(size_t)node * 32 + j];
        acc = make_float4(self.x * w, self.y * w, self.z * w, self.w * w);
    }

    int k   = rowptr[node] + half;
    int end = rowptr[node + 1];

    // 4-deep unroll over this half's edges (stride 2)
    for (; k + 6 < end; k += 8) {
        int s0 = esrc[k], s1 = esrc[k + 2], s2 = esrc[k + 4], s3 = esrc[k + 6];
        float n0 = dinv[s0] * di, n1 = dinv[s1] * di, n2 = dinv[s2] * di, n3 = dinv[s3] * di;
        float4 v0 = h4[(size_t)s0 * 32 + j];
        float4 v1 = h4[(size_t)s1 * 32 + j];
        float4 v2 = h4[(size_t)s2 * 32 + j];
        float4 v3 = h4[(size_t)s3 * 32 + j];
        acc.x += v0.x * n0 + v1.x * n1 + v2.x * n2 + v3.x * n3;
        acc.y += v0.y * n0 + v1.y * n1 + v2.y * n2 + v3.y * n3;
        acc.z += v0.z * n0 + v1.z * n1 + v2.z * n2 + v3.z * n3;
        acc.w += v0.w * n0 + v1.w * n1 + v2.w * n2 + v3.w * n3;
    }
    for (; k < end; k += 2) {
        int s0 = esrc[k];
        float n0 = dinv[s0] * di;
        float4 v0 = h4[(size_t)s0 * 32 + j];
        acc.x += v0.x * n0; acc.y += v0.y * n0;
        acc.z += v0.z * n0; acc.w += v0.w * n0;
    }

    // combine even/odd halves: lane L (<32) += lane L+32
    acc.x += __shfl_xor(acc.x, 32);
    acc.y += __shfl_xor(acc.y, 32);
    acc.z += __shfl_xor(acc.z, 32);
    acc.w += __shfl_xor(acc.w, 32);

    if (lane < 32) {
        if (j < 16) {
            float4 b = ((const float4*)bmu)[j];
            ((float4*)out_mu)[(size_t)node * 16 + j] =
                make_float4(acc.x + b.x, acc.y + b.y, acc.z + b.z, acc.w + b.w);
        } else {
            int jj = j - 16;
            float4 b = ((const float4*)bls)[jj];
            ((float4*)out_ls)[(size_t)node * 16 + jj] =
                make_float4(acc.x + b.x, acc.y + b.y, acc.z + b.z, acc.w + b.w);
        }
    }
}

// ---------------------------------------------------------------- launch
extern "C" void kernel_launch(void* const* d_in, const int* in_sizes, int n_in,
                              void* d_out, int out_size, void* d_ws, size_t ws_size,
                              hipStream_t stream) {
    const float* x   = (const float*)d_in[0];
    const void*  ei  = d_in[1];
    const float* Wmu = (const float*)d_in[2];
    const float* bmu = (const float*)d_in[3];
    const float* Wls = (const float*)d_in[4];
    const float* bls = (const float*)d_in[5];

    const int N = in_sizes[0] / IN_C;
    const int E = in_sizes[1] / 2;

    float* out_mu = (float*)d_out;
    float* out_ls = (float*)d_out + (size_t)N * OC;

    // workspace layout (256B aligned)
    char* w = (char*)d_ws;
    auto align256 = [](size_t v) { return (v + 255) & ~(size_t)255; };
    int*   flag   = (int*)w;                  size_t off = 256;
    int*   bsum   = (int*)(w + off);          off += 256;
    int*   bbase  = (int*)(w + off);          off += 256;
    int*   cnt    = (int*)(w + off);          off += align256((size_t)N * 4);
    int*   cursor = (int*)(w + off);          off += align256((size_t)N * 4);
    float* dinv   = (float*)(w + off);        off += align256((size_t)N * 4);
    int*   rowptr = (int*)(w + off);          off += align256((size_t)(N + 1) * 4);
    int*   esrc   = (int*)(w + off);          off += align256((size_t)E * 4);
    float* h      = (float*)(w + off);        off += align256((size_t)N * HC * 4);

    int n_scan = E < 4096 ? E : 4096;
    hipLaunchKernelGGL(k_detect, dim3(1), dim3(256), 0, stream, ei, n_scan, (long long)N, flag);

    int gN = (N + 255) / 256;
    hipLaunchKernelGGL(k_zero, dim3(gN), dim3(256), 0, stream, cnt, N);

    int gE4 = (E + 1023) / 1024;
    hipLaunchKernelGGL(k_count, dim3(gE4), dim3(256), 0, stream, ei, cnt, E, flag);

    int nb = (N + SCHUNK - 1) / SCHUNK;    // 25 blocks for N=100k (<=64 req'd by scan2 buffer)
    hipLaunchKernelGGL(k_scan1, dim3(nb), dim3(256), 0, stream, cnt, bsum, N);
    hipLaunchKernelGGL(k_scan2, dim3(1), dim3(64), 0, stream, bsum, bbase, nb);
    hipLaunchKernelGGL(k_scan3, dim3(nb), dim3(256), 0, stream, cnt, bbase, rowptr, dinv, cursor, N);

    hipLaunchKernelGGL(k_fill, dim3(gE4), dim3(256), 0, stream, ei, rowptr, cursor, esrc, E, flag);

    int gG = (N + 127) / 128;
    hipLaunchKernelGGL(k_gemm, dim3(gG), dim3(256), 0, stream, x, Wmu, Wls, h, N);

    int gO = (N + 3) / 4;
    hipLaunchKernelGGL(k_out, dim3(gO), dim3(256), 0, stream, h, rowptr, esrc, dinv, bmu, bls, out_mu, out_ls, N);
}